// Round 1
// baseline (582.943 us; speedup 1.0000x reference)
//
#include <hip/hip_runtime.h>
#include <hip/hip_bf16.h>
#include <math.h>

// Problem constants (from reference)
constexpr int MM = 10000;   // N_NODES
constexpr int DD = 256;     // D_IN == D_OUT
constexpr int EE = 320000;  // N_EDGES

// ---------------------------------------------------------------------------
// GEMM: H[m][n] = sum_k X[m][k] * W[n][k]   (x @ W.T), fp32
// 64x64 tile, BK=16, 256 threads, 4x4 micro-tile, transposed LDS tiles for
// vectorized (float4) LDS reads; stride 68 floats to avoid bank conflicts.
// ---------------------------------------------------------------------------
#define BM 64
#define BN 64
#define BK 16
#define LDT 68

__global__ __launch_bounds__(256) void gemm_h(const float* __restrict__ X,
                                              const float* __restrict__ W,
                                              float* __restrict__ H) {
    __shared__ float xs[BK][LDT];  // [k][m]
    __shared__ float ws[BK][LDT];  // [k][n]
    const int tid = threadIdx.x;
    const int bm = blockIdx.x * BM;
    const int bn = blockIdx.y * BN;
    const int lr = tid >> 2;          // 0..63 (tile row)
    const int lc = (tid & 3) << 2;    // 0,4,8,12 (k offset)
    const int tx = tid & 15;          // 0..15
    const int ty = tid >> 4;          // 0..15

    float acc[4][4] = {};

    for (int k0 = 0; k0 < DD; k0 += BK) {
        const int gr = bm + lr;
        float4 xv = make_float4(0.f, 0.f, 0.f, 0.f);
        if (gr < MM) xv = *(const float4*)(X + (size_t)gr * DD + k0 + lc);
        float4 wv = *(const float4*)(W + (size_t)(bn + lr) * DD + k0 + lc);
        xs[lc + 0][lr] = xv.x; xs[lc + 1][lr] = xv.y;
        xs[lc + 2][lr] = xv.z; xs[lc + 3][lr] = xv.w;
        ws[lc + 0][lr] = wv.x; ws[lc + 1][lr] = wv.y;
        ws[lc + 2][lr] = wv.z; ws[lc + 3][lr] = wv.w;
        __syncthreads();
#pragma unroll
        for (int k = 0; k < BK; ++k) {
            float4 xr4 = *(const float4*)(&xs[k][ty << 2]);
            float4 wr4 = *(const float4*)(&ws[k][tx << 2]);
            float xr[4] = {xr4.x, xr4.y, xr4.z, xr4.w};
            float wr[4] = {wr4.x, wr4.y, wr4.z, wr4.w};
#pragma unroll
            for (int i = 0; i < 4; ++i)
#pragma unroll
                for (int j = 0; j < 4; ++j) acc[i][j] += xr[i] * wr[j];
        }
        __syncthreads();
    }
#pragma unroll
    for (int i = 0; i < 4; ++i) {
        const int r = bm + (ty << 2) + i;
        if (r < MM) {
            *(float4*)(H + (size_t)r * DD + bn + (tx << 2)) =
                make_float4(acc[i][0], acc[i][1], acc[i][2], acc[i][3]);
        }
    }
}

// ---------------------------------------------------------------------------
// Per-node dots: s_src[n] = att_src . h[n], s_dst[n] = att_dst . h[n]
// One wave (64 lanes) per node, float4 per lane (64*4 = 256).
// ---------------------------------------------------------------------------
__global__ __launch_bounds__(256) void node_dots(const float* __restrict__ h,
                                                 const float* __restrict__ att_src,
                                                 const float* __restrict__ att_dst,
                                                 float* __restrict__ s_src,
                                                 float* __restrict__ s_dst) {
    const int wave = threadIdx.x >> 6;
    const int lane = threadIdx.x & 63;
    const int node = blockIdx.x * 4 + wave;
    if (node >= MM) return;
    float4 a = ((const float4*)att_src)[lane];
    float4 b = ((const float4*)att_dst)[lane];
    float4 v = ((const float4*)(h + (size_t)node * DD))[lane];
    float ds = v.x * a.x + v.y * a.y + v.z * a.z + v.w * a.w;
    float dd = v.x * b.x + v.y * b.y + v.z * b.z + v.w * b.w;
#pragma unroll
    for (int off = 32; off > 0; off >>= 1) {
        ds += __shfl_xor(ds, off);
        dd += __shfl_xor(dd, off);
    }
    if (lane == 0) { s_src[node] = ds; s_dst[node] = dd; }
}

// ---------------------------------------------------------------------------
// Per-edge: score[e] = LeakyReLU(s_src[src]+s_dst[dst]); count degrees.
// ---------------------------------------------------------------------------
__global__ __launch_bounds__(256) void edge_score(const int* __restrict__ src,
                                                  const int* __restrict__ dst,
                                                  const float* __restrict__ s_src,
                                                  const float* __restrict__ s_dst,
                                                  float* __restrict__ score,
                                                  int* __restrict__ deg) {
    const int e = blockIdx.x * blockDim.x + threadIdx.x;
    if (e >= EE) return;
    const int s = src[e], d = dst[e];
    float sc = s_src[s] + s_dst[d];
    sc = (sc >= 0.f) ? sc : 0.2f * sc;
    score[e] = sc;
    atomicAdd(&deg[d], 1);
}

// ---------------------------------------------------------------------------
// Exclusive scan over deg (10000) -> row_off[10001], cursor copy.
// Single block of 1024, chunked Hillis-Steele with carry.
// ---------------------------------------------------------------------------
__global__ __launch_bounds__(1024) void scan_deg(const int* __restrict__ deg,
                                                 int* __restrict__ row_off,
                                                 int* __restrict__ cursor) {
    __shared__ int buf[1024];
    __shared__ int carry;
    const int tid = threadIdx.x;
    if (tid == 0) { carry = 0; row_off[0] = 0; }
    __syncthreads();
    for (int base = 0; base < MM; base += 1024) {
        const int i = base + tid;
        const int v = (i < MM) ? deg[i] : 0;
        buf[tid] = v;
        __syncthreads();
        for (int off = 1; off < 1024; off <<= 1) {
            int t = (tid >= off) ? buf[tid - off] : 0;
            __syncthreads();
            buf[tid] += t;
            __syncthreads();
        }
        const int inc = buf[tid] + carry;  // inclusive prefix incl. carry
        if (i < MM) {
            row_off[i + 1] = inc;
            cursor[i] = inc - v;  // exclusive prefix
        }
        __syncthreads();
        if (tid == 1023) carry = inc;
        __syncthreads();
    }
}

// ---------------------------------------------------------------------------
// Scatter edge ids into CSR order by dst.
// ---------------------------------------------------------------------------
__global__ __launch_bounds__(256) void edge_scatter(const int* __restrict__ dst,
                                                    int* __restrict__ cursor,
                                                    int* __restrict__ csr) {
    const int e = blockIdx.x * blockDim.x + threadIdx.x;
    if (e >= EE) return;
    const int pos = atomicAdd(&cursor[dst[e]], 1);
    csr[pos] = e;
}

// ---------------------------------------------------------------------------
// Fused per-node: segment softmax + attention-matrix scatter + aggregation.
// One block (256 threads) per dst node; thread t owns output channel t.
// ---------------------------------------------------------------------------
__global__ __launch_bounds__(256) void node_softmax_agg(
    const float* __restrict__ h, const float* __restrict__ score,
    float* __restrict__ expv, const int* __restrict__ src,
    const int* __restrict__ csr, const int* __restrict__ row_off,
    float* __restrict__ out, float* __restrict__ att) {
    const int node = blockIdx.x;
    const int tid = threadIdx.x;
    const int r0 = row_off[node];
    const int r1 = row_off[node + 1];
    const int deg = r1 - r0;

    if (deg == 0) {  // keep own transformed features
        out[(size_t)node * DD + tid] = h[(size_t)node * DD + tid];
        return;
    }

    __shared__ float red[256];
    // phase 1: segment max
    float m = -INFINITY;
    for (int i = r0 + tid; i < r1; i += 256) m = fmaxf(m, score[csr[i]]);
    red[tid] = m;
    __syncthreads();
    for (int s = 128; s > 0; s >>= 1) {
        if (tid < s) red[tid] = fmaxf(red[tid], red[tid + s]);
        __syncthreads();
    }
    m = red[0];
    __syncthreads();
    // phase 2: exp + segment sum
    float sum = 0.f;
    for (int i = r0 + tid; i < r1; i += 256) {
        const int e = csr[i];
        const float ex = expf(score[e] - m);
        expv[e] = ex;
        sum += ex;
    }
    red[tid] = sum;
    __syncthreads();
    for (int s = 128; s > 0; s >>= 1) {
        if (tid < s) red[tid] += red[tid + s];
        __syncthreads();
    }
    const float inv = 1.0f / red[0];
    __syncthreads();

    // phase 3+4: chunked alpha + attention scatter + aggregation
    __shared__ float a_s[64];
    __shared__ int s_s[64];
    float acc = 0.f;
    for (int c = r0; c < r1; c += 64) {
        const int cnt = min(64, r1 - c);
        if (tid < cnt) {
            const int e = csr[c + tid];
            const float a = expv[e] * inv;
            const int sn = src[e];
            a_s[tid] = a;
            s_s[tid] = sn;
            att[(size_t)sn * MM + node] = a;  // attention_matrix[src, dst]
        }
        __syncthreads();
        for (int j = 0; j < cnt; ++j) acc += a_s[j] * h[(size_t)s_s[j] * DD + tid];
        __syncthreads();
    }
    out[(size_t)node * DD + tid] = acc;
}

// ---------------------------------------------------------------------------
extern "C" void kernel_launch(void* const* d_in, const int* in_sizes, int n_in,
                              void* d_out, int out_size, void* d_ws, size_t ws_size,
                              hipStream_t stream) {
    const float* x       = (const float*)d_in[0];  // [10000,256]
    const float* W       = (const float*)d_in[1];  // [256,256]
    const float* att_src = (const float*)d_in[2];  // [1,256]
    const float* att_dst = (const float*)d_in[3];  // [1,256]
    const int*   eidx    = (const int*)d_in[4];    // [2,320000]
    const int* src = eidx;
    const int* dst = eidx + EE;

    float* out_feat = (float*)d_out;               // [10000,256]
    float* att      = out_feat + (size_t)MM * DD;  // [10000,10000]

    // workspace layout
    float* h      = (float*)d_ws;                    // MM*DD
    float* s_src  = h + (size_t)MM * DD;             // MM
    float* s_dst  = s_src + MM;                      // MM
    float* score  = s_dst + MM;                      // EE
    float* expv   = score + EE;                      // EE
    int*   deg    = (int*)(expv + EE);               // MM
    int*   row_off= deg + MM;                        // MM+1
    int*   cursor = row_off + MM + 1;                // MM
    int*   csr    = cursor + MM;                     // EE

    // zero the dense attention matrix (dominant HBM cost: 400 MB)
    hipMemsetAsync(att, 0, (size_t)MM * MM * sizeof(float), stream);
    // zero degree counters
    hipMemsetAsync(deg, 0, MM * sizeof(int), stream);

    dim3 gemm_grid((MM + BM - 1) / BM, DD / BN);
    gemm_h<<<gemm_grid, 256, 0, stream>>>(x, W, h);

    node_dots<<<(MM + 3) / 4, 256, 0, stream>>>(h, att_src, att_dst, s_src, s_dst);

    edge_score<<<(EE + 255) / 256, 256, 0, stream>>>(src, dst, s_src, s_dst, score, deg);

    scan_deg<<<1, 1024, 0, stream>>>(deg, row_off, cursor);

    edge_scatter<<<(EE + 255) / 256, 256, 0, stream>>>(dst, cursor, csr);

    node_softmax_agg<<<MM, 256, 0, stream>>>(h, score, expv, src, csr, row_off,
                                             out_feat, att);
}

// Round 2
// 563.992 us; speedup vs baseline: 1.0336x; 1.0336x over previous
//
#include <hip/hip_runtime.h>
#include <hip/hip_bf16.h>
#include <math.h>

constexpr int MM = 10000;   // N_NODES
constexpr int DD = 256;     // D_IN == D_OUT
constexpr int EE = 320000;  // N_EDGES

// attention-matrix zero-fill partition (float4 units; total = MM*MM/4 = 25e6)
constexpr size_t ZT = (size_t)MM * MM / 4;   // 25,000,000
constexpr size_t Z1 = 16000000;              // gemm slice      (256 MB)
constexpr size_t Z2 = 20500000;              // node_dots slice (72 MB)
                                             // edge_score gets [Z2, ZT) (72 MB)

__device__ __forceinline__ void zero_att_slice(float4* att4, size_t lo, size_t hi) {
    const size_t stride = (size_t)gridDim.x * blockDim.x;
    for (size_t p = lo + (size_t)blockIdx.x * blockDim.x + threadIdx.x; p < hi; p += stride)
        att4[p] = make_float4(0.f, 0.f, 0.f, 0.f);
}

// ---------------------------------------------------------------------------
// GEMM: H = X @ W^T  (fp32), 64x64 tile, BK=16, 256 thr, 4x4 micro-tile.
// Prologue: stream-zero 256 MB of the attention matrix (overlaps compute).
// ---------------------------------------------------------------------------
#define BKK 16
#define LDT 68

__global__ __launch_bounds__(256) void gemm_h(const float* __restrict__ X,
                                              const float* __restrict__ W,
                                              float* __restrict__ H,
                                              float4* __restrict__ att4) {
    zero_att_slice(att4, 0, Z1);

    __shared__ float xs[BKK][LDT];  // [k][m]
    __shared__ float ws[BKK][LDT];  // [k][n]
    const int tid = threadIdx.x;
    const int bid = blockIdx.x;
    const int bm = (bid % 157) * 64;
    const int bn = (bid / 157) * 64;
    const int lr = tid >> 2;          // 0..63
    const int lc = (tid & 3) << 2;    // 0,4,8,12
    const int tx = tid & 15;
    const int ty = tid >> 4;

    float acc[4][4] = {};

    for (int k0 = 0; k0 < DD; k0 += BKK) {
        const int gr = bm + lr;
        float4 xv = make_float4(0.f, 0.f, 0.f, 0.f);
        if (gr < MM) xv = *(const float4*)(X + (size_t)gr * DD + k0 + lc);
        float4 wv = *(const float4*)(W + (size_t)(bn + lr) * DD + k0 + lc);
        xs[lc + 0][lr] = xv.x; xs[lc + 1][lr] = xv.y;
        xs[lc + 2][lr] = xv.z; xs[lc + 3][lr] = xv.w;
        ws[lc + 0][lr] = wv.x; ws[lc + 1][lr] = wv.y;
        ws[lc + 2][lr] = wv.z; ws[lc + 3][lr] = wv.w;
        __syncthreads();
#pragma unroll
        for (int k = 0; k < BKK; ++k) {
            float4 xr4 = *(const float4*)(&xs[k][ty << 2]);
            float4 wr4 = *(const float4*)(&ws[k][tx << 2]);
            float xr[4] = {xr4.x, xr4.y, xr4.z, xr4.w};
            float wr[4] = {wr4.x, wr4.y, wr4.z, wr4.w};
#pragma unroll
            for (int i = 0; i < 4; ++i)
#pragma unroll
                for (int j = 0; j < 4; ++j) acc[i][j] += xr[i] * wr[j];
        }
        __syncthreads();
    }
#pragma unroll
    for (int i = 0; i < 4; ++i) {
        const int r = bm + (ty << 2) + i;
        if (r < MM) {
            *(float4*)(H + (size_t)r * DD + bn + (tx << 2)) =
                make_float4(acc[i][0], acc[i][1], acc[i][2], acc[i][3]);
        }
    }
}

// ---------------------------------------------------------------------------
// Per-node dots, wave per node: s_src[n] = att_src.h[n], s_dst[n] = att_dst.h[n]
// ---------------------------------------------------------------------------
__global__ __launch_bounds__(256) void node_dots(const float* __restrict__ h,
                                                 const float* __restrict__ att_src,
                                                 const float* __restrict__ att_dst,
                                                 float* __restrict__ s_src,
                                                 float* __restrict__ s_dst,
                                                 float4* __restrict__ att4) {
    zero_att_slice(att4, Z1, Z2);
    const int wv = threadIdx.x >> 6, lane = threadIdx.x & 63;
    const int node = blockIdx.x * 4 + wv;
    if (node >= MM) return;
    float4 a = ((const float4*)att_src)[lane];
    float4 b = ((const float4*)att_dst)[lane];
    float4 v = ((const float4*)h)[(size_t)node * 64 + lane];
    float ds = v.x * a.x + v.y * a.y + v.z * a.z + v.w * a.w;
    float dd = v.x * b.x + v.y * b.y + v.z * b.z + v.w * b.w;
#pragma unroll
    for (int off = 32; off; off >>= 1) {
        ds += __shfl_xor(ds, off);
        dd += __shfl_xor(dd, off);
    }
    if (lane == 0) { s_src[node] = ds; s_dst[node] = dd; }
}

// ---------------------------------------------------------------------------
// Per-edge score + degree count.  1250*256 == EE exactly.
// ---------------------------------------------------------------------------
__global__ __launch_bounds__(256) void edge_score(const int* __restrict__ src,
                                                  const int* __restrict__ dst,
                                                  const float* __restrict__ s_src,
                                                  const float* __restrict__ s_dst,
                                                  float* __restrict__ score,
                                                  int* __restrict__ deg,
                                                  float4* __restrict__ att4) {
    zero_att_slice(att4, Z2, ZT);
    const int e = blockIdx.x * 256 + threadIdx.x;
    const int s = src[e], d = dst[e];
    float sc = s_src[s] + s_dst[d];
    sc = (sc >= 0.f) ? sc : 0.2f * sc;
    score[e] = sc;
    atomicAdd(&deg[d], 1);
}

// ---------------------------------------------------------------------------
// Exclusive scan of deg -> row_off[MM+1], cursor.  1 block, 1024 thr, 2 barriers.
// Thread t serially owns deg[t*10 .. t*10+10).
// ---------------------------------------------------------------------------
__global__ __launch_bounds__(1024) void scan_deg(const int* __restrict__ deg,
                                                 int* __restrict__ row_off,
                                                 int* __restrict__ cursor) {
    constexpr int C = 10;  // 1024*10 >= MM
    __shared__ int wsum[16];
    const int t = threadIdx.x, wv = t >> 6, lane = t & 63;
    const int i0 = t * C;
    int total = 0;
#pragma unroll
    for (int k = 0; k < C; ++k) {
        const int i = i0 + k;
        total += (i < MM) ? deg[i] : 0;
    }
    int incl = total;
#pragma unroll
    for (int off = 1; off < 64; off <<= 1) {
        int u = __shfl_up(incl, off);
        if (lane >= off) incl += u;
    }
    if (lane == 63) wsum[wv] = incl;
    __syncthreads();
    if (t < 16) {
        int v = wsum[t];
#pragma unroll
        for (int off = 1; off < 16; off <<= 1) {
            int u = __shfl_up(v, off);
            if (t >= off) v += u;
        }
        wsum[t] = v;
    }
    __syncthreads();
    const int wave_excl = (wv == 0) ? 0 : wsum[wv - 1];
    int run = wave_excl + incl - total;  // global exclusive prefix for this thread
#pragma unroll
    for (int k = 0; k < C; ++k) {
        const int i = i0 + k;
        if (i < MM) {
            const int v = deg[i];
            cursor[i] = run;
            run += v;
            row_off[i + 1] = run;
        }
    }
    if (t == 0) row_off[0] = 0;
}

// ---------------------------------------------------------------------------
// Scatter edge ids into CSR order by dst.
// ---------------------------------------------------------------------------
__global__ __launch_bounds__(256) void edge_scatter(const int* __restrict__ dst,
                                                    int* __restrict__ cursor,
                                                    int* __restrict__ csr) {
    const int e = blockIdx.x * 256 + threadIdx.x;
    const int pos = atomicAdd(&cursor[dst[e]], 1);
    csr[pos] = e;
}

// ---------------------------------------------------------------------------
// Wave-per-node softmax + attention scatter + aggregation.
// Barrier-free, LDS-free: scores/edge-ids for up to 4 chunks (deg<=256) cached
// in registers (static indices); shfl reductions; shfl-broadcast aggregation.
// Dynamic overflow path keeps correctness for deg>256 (never hit here: max~60).
// ---------------------------------------------------------------------------
__global__ __launch_bounds__(256) void node_agg(const float* __restrict__ h,
                                                const float* __restrict__ score,
                                                const int* __restrict__ src,
                                                const int* __restrict__ csr,
                                                const int* __restrict__ row_off,
                                                float* __restrict__ out,
                                                float* __restrict__ att) {
    const int wv = threadIdx.x >> 6, lane = threadIdx.x & 63;
    const int node = blockIdx.x * 4 + wv;
    if (node >= MM) return;
    const int r0 = row_off[node], r1 = row_off[node + 1];
    const float4* h4 = (const float4*)h;
    float4* out4 = (float4*)out;

    if (r0 == r1) {  // no incoming edges: keep own transformed features
        out4[(size_t)node * 64 + lane] = h4[(size_t)node * 64 + lane];
        return;
    }

    // phase 1: max (cache first 4 chunks in registers)
    int e_reg[4];
    float s_reg[4];
    float m = -INFINITY;
#pragma unroll
    for (int c = 0; c < 4; ++c) {
        const int i = r0 + c * 64 + lane;
        const bool vld = i < r1;
        const int e = vld ? csr[i] : 0;
        const float s = vld ? score[e] : -INFINITY;
        e_reg[c] = e; s_reg[c] = s;
        m = fmaxf(m, s);
    }
    for (int i = r0 + 256 + lane; i < r1; i += 64) m = fmaxf(m, score[csr[i]]);
#pragma unroll
    for (int off = 32; off; off >>= 1) m = fmaxf(m, __shfl_xor(m, off));

    // phase 2: exp + sum (s_reg becomes ex)
    float sum = 0.f;
#pragma unroll
    for (int c = 0; c < 4; ++c) {
        const int i = r0 + c * 64 + lane;
        const float ex = (i < r1) ? expf(s_reg[c] - m) : 0.f;
        s_reg[c] = ex;
        sum += ex;
    }
    for (int i = r0 + 256 + lane; i < r1; i += 64) sum += expf(score[csr[i]] - m);
#pragma unroll
    for (int off = 32; off; off >>= 1) sum += __shfl_xor(sum, off);
    const float inv = 1.f / sum;

    // phase 3: alpha scatter + shfl-broadcast aggregation (float4 channels)
    float4 acc = make_float4(0.f, 0.f, 0.f, 0.f);
#pragma unroll
    for (int c = 0; c < 4; ++c) {
        const int base = r0 + c * 64;
        if (base < r1) {
            const int i = base + lane;
            float a = 0.f; int sn = 0;
            if (i < r1) {
                a = s_reg[c] * inv;
                sn = src[e_reg[c]];
                att[(size_t)sn * MM + node] = a;
            }
            const int cnt = min(64, r1 - base);
            for (int j = 0; j < cnt; ++j) {
                const float aj = __shfl(a, j);
                const int sj = __shfl(sn, j);
                const float4 hv = h4[(size_t)sj * 64 + lane];
                acc.x += aj * hv.x; acc.y += aj * hv.y;
                acc.z += aj * hv.z; acc.w += aj * hv.w;
            }
        }
    }
    for (int base = r0 + 256; base < r1; base += 64) {  // overflow (deg>256)
        const int i = base + lane;
        float a = 0.f; int sn = 0;
        if (i < r1) {
            const int e = csr[i];
            a = expf(score[e] - m) * inv;
            sn = src[e];
            att[(size_t)sn * MM + node] = a;
        }
        const int cnt = min(64, r1 - base);
        for (int j = 0; j < cnt; ++j) {
            const float aj = __shfl(a, j);
            const int sj = __shfl(sn, j);
            const float4 hv = h4[(size_t)sj * 64 + lane];
            acc.x += aj * hv.x; acc.y += aj * hv.y;
            acc.z += aj * hv.z; acc.w += aj * hv.w;
        }
    }
    out4[(size_t)node * 64 + lane] = acc;
}

// ---------------------------------------------------------------------------
extern "C" void kernel_launch(void* const* d_in, const int* in_sizes, int n_in,
                              void* d_out, int out_size, void* d_ws, size_t ws_size,
                              hipStream_t stream) {
    const float* x       = (const float*)d_in[0];
    const float* W       = (const float*)d_in[1];
    const float* att_src = (const float*)d_in[2];
    const float* att_dst = (const float*)d_in[3];
    const int*   eidx    = (const int*)d_in[4];
    const int* src = eidx;
    const int* dst = eidx + EE;

    float* out_feat = (float*)d_out;               // [10000,256]
    float* att      = out_feat + (size_t)MM * DD;  // [10000,10000]
    float4* att4    = (float4*)att;

    float* h       = (float*)d_ws;                  // MM*DD
    float* s_src   = h + (size_t)MM * DD;           // MM
    float* s_dst   = s_src + MM;                    // MM
    float* score   = s_dst + MM;                    // EE
    int*   deg     = (int*)(score + EE);            // MM
    int*   row_off = deg + MM;                      // MM+1
    int*   cursor  = row_off + MM + 1;              // MM
    int*   csr     = cursor + MM;                   // EE

    hipMemsetAsync(deg, 0, MM * sizeof(int), stream);

    gemm_h<<<628, 256, 0, stream>>>(x, W, h, att4);
    node_dots<<<2500, 256, 0, stream>>>(h, att_src, att_dst, s_src, s_dst, att4);
    edge_score<<<1250, 256, 0, stream>>>(src, dst, s_src, s_dst, score, deg, att4);
    scan_deg<<<1, 1024, 0, stream>>>(deg, row_off, cursor);
    edge_scatter<<<1250, 256, 0, stream>>>(dst, cursor, csr);
    node_agg<<<2500, 256, 0, stream>>>(h, score, src, csr, row_off, out_feat, att);
}